// Round 2
// baseline (523.432 us; speedup 1.0000x reference)
//
#include <hip/hip_runtime.h>
#include <hip/hip_bf16.h>
#include <stdint.h>

typedef __bf16 bf16x8_t __attribute__((ext_vector_type(8)));
typedef short  s16x8_t  __attribute__((ext_vector_type(8)));
typedef float  f32x4_t  __attribute__((ext_vector_type(4)));

#define NTOK 3072
#define NHEAD 8

__device__ __forceinline__ unsigned short f2bf(float f) {
  union { float f; uint32_t u; } v; v.f = f;
  uint32_t r = v.u + 0x7fffu + ((v.u >> 16) & 1u);
  return (unsigned short)(r >> 16);
}

__device__ __forceinline__ void gload_lds16(const void* g, void* lds) {
  __builtin_amdgcn_global_load_lds(
      (const __attribute__((address_space(1))) uint32_t*)g,
      (__attribute__((address_space(3))) uint32_t*)lds, 16, 0, 0);
}

// ---------------- prep kernels ----------------

// qkvwT[c][d], c = op*2048 + h*256 + e  (6144 x 256), from W_op[h][d][e]
__global__ void prep_qkv_w(const float* __restrict__ WQ, const float* __restrict__ WK,
                           const float* __restrict__ WV, unsigned short* __restrict__ out) {
  int idx = blockIdx.x * 256 + threadIdx.x;      // c = blockIdx.x, d = threadIdx.x
  int d = idx & 255;
  int c = idx >> 8;
  int e = c & 255, h = (c >> 8) & 7, op = c >> 11;
  const float* W = (op == 0) ? WQ : ((op == 1) ? WK : WV);
  out[idx] = f2bf(W[(h * 256 + d) * 256 + e]);
}

// out[e][d] = bf16(W[d][e]);  W is (Din x Dout), out is (Dout x Din)
__global__ void prep_T(const float* __restrict__ W, unsigned short* __restrict__ out,
                       int Din, int Dout) {
  int idx = blockIdx.x * 256 + threadIdx.x;
  int d = idx % Din, e = idx / Din;
  out[idx] = f2bf(W[d * Dout + e]);
}

// xa[n][0:256] = bf16(x[n][:]) ; xa has row stride 512
__global__ void prep_x(const float* __restrict__ x, unsigned short* __restrict__ xa) {
  int idx = blockIdx.x * 256 + threadIdx.x;
  int n = idx >> 8, d = idx & 255;
  xa[(size_t)n * 512 + d] = f2bf(x[idx]);
}

// ---------------- generic MFMA GEMM (m97-style, 128x128x32, swizzled LDS) --------
// C[M x Ncols] = A[M x K] (bf16, lda) @ Bt[Ncols x K]^T (bf16, ldb)
// flags: 1 = relu, 2 = bf16 out, 4 = multiply (acc+bias) by rsqrt(deg[row])
__global__ __launch_bounds__(256, 2) void gemm_kernel(
    const unsigned short* __restrict__ A, int lda,
    const unsigned short* __restrict__ B, int ldb,
    void* __restrict__ Cout, int ldc, int K,
    const float* __restrict__ bias,
    const float* __restrict__ resid, int ldr,
    const float* __restrict__ deg, int flags) {
  __shared__ unsigned short As[128 * 32];
  __shared__ unsigned short Bs[128 * 32];
  const int t = threadIdx.x;
  const int w = t >> 6, l = t & 63;
  const int l15 = l & 15, lhi = l >> 4;
  const int row0 = blockIdx.y * 128, col0 = blockIdx.x * 128;
  const int wr = (w >> 1) * 64, wc = (w & 1) * 64;

  f32x4_t acc[4][4];
#pragma unroll
  for (int m = 0; m < 4; ++m)
#pragma unroll
    for (int n = 0; n < 4; ++n) acc[m][n] = (f32x4_t){0.f, 0.f, 0.f, 0.f};

  const int srow = l >> 2;          // row within 16-row chunk
  const int spc  = (l & 3) * 16;    // physical col byte
  const int nkt = K >> 5;
  for (int kt = 0; kt < nkt; ++kt) {
    __syncthreads();
#pragma unroll
    for (int i = 0; i < 2; ++i) {
      int c = w * 2 + i;
      int ar = c * 16 + srow;                        // tile row 0..127
      int lcb = spc ^ (((ar >> 1) & 3) << 4);        // logical col byte (swizzle inverse)
      gload_lds16(A + (size_t)(row0 + ar) * lda + kt * 32 + (lcb >> 1), &As[c * 512]);
      gload_lds16(B + (size_t)(col0 + ar) * ldb + kt * 32 + (lcb >> 1), &Bs[c * 512]);
    }
    __syncthreads();
    bf16x8_t af[4], bfr[4];
#pragma unroll
    for (int m = 0; m < 4; ++m) {
      int ar = wr + m * 16 + l15;
      af[m] = *(const bf16x8_t*)(&As[(ar * 64 + ((lhi * 16) ^ (((ar >> 1) & 3) << 4))) >> 1]);
      int br = wc + m * 16 + l15;
      bfr[m] = *(const bf16x8_t*)(&Bs[(br * 64 + ((lhi * 16) ^ (((br >> 1) & 3) << 4))) >> 1]);
    }
#pragma unroll
    for (int m = 0; m < 4; ++m)
#pragma unroll
      for (int n = 0; n < 4; ++n)
        acc[m][n] = __builtin_amdgcn_mfma_f32_16x16x32_bf16(af[m], bfr[n], acc[m][n], 0, 0, 0);
  }

  const bool relu = flags & 1, obf = flags & 2, dsc = flags & 4;
#pragma unroll
  for (int m = 0; m < 4; ++m) {
#pragma unroll
    for (int r = 0; r < 4; ++r) {
      int grow = row0 + wr + m * 16 + lhi * 4 + r;
      float sc = dsc ? rsqrtf(deg[grow]) : 1.0f;
#pragma unroll
      for (int n = 0; n < 4; ++n) {
        int gcol = col0 + wc + n * 16 + l15;
        float v = acc[m][n][r];
        if (bias) v += bias[gcol];
        v *= sc;
        if (resid) v += resid[(size_t)grow * ldr + gcol];
        if (relu) v = fmaxf(v, 0.f);
        if (obf)
          ((unsigned short*)Cout)[(size_t)grow * ldc + gcol] = f2bf(v);
        else
          ((float*)Cout)[(size_t)grow * ldc + gcol] = v;
      }
    }
  }
}

// ---------------- flash attention ----------------
// qkv: (N x 6144) bf16 rows = [Q heads | K heads | V heads]; out: attn_cat (N x 2048) bf16
// block: 4 waves x 16 Q rows = 64 Q rows; KV block = 32.
__global__ __launch_bounds__(256, 2) void flash_kernel(
    const unsigned short* __restrict__ qkv, unsigned short* __restrict__ acat) {
  __shared__ unsigned short Ks[32 * 256];   // swizzled: byte ^= (row&7)<<4
  __shared__ unsigned short Vt[256 * 32];   // transposed, swizzled: byte ^= ((e>>1)&3)<<4
  __shared__ unsigned short Ps[4][16 * 32]; // per-wave P, swizzled: byte ^= ((row>>1)&3)<<4
  const int h = blockIdx.y;
  const int q0 = blockIdx.x * 64;
  const int t = threadIdx.x, w = t >> 6, l = t & 63;
  const int l15 = l & 15, lhi = l >> 4;

  // Q fragments (16 rows x 256) held in registers for the whole loop
  bf16x8_t qf[8];
  {
    const unsigned short* Qb = qkv + (size_t)(q0 + w * 16 + l15) * 6144 + h * 256 + lhi * 8;
#pragma unroll
    for (int kk = 0; kk < 8; ++kk) qf[kk] = *(const bf16x8_t*)(Qb + kk * 32);
  }
  f32x4_t o[16];
#pragma unroll
  for (int et = 0; et < 16; ++et) o[et] = (f32x4_t){0.f, 0.f, 0.f, 0.f};
  float m_run[4] = {-1e30f, -1e30f, -1e30f, -1e30f};
  float l_run[4] = {0.f, 0.f, 0.f, 0.f};

  const int vn0 = (t & 7) * 4;        // V-staging: 4 kv rows
  const int ve0 = (t >> 3) * 8;       // 8 features

  for (int nt = 0; nt < 96; ++nt) {
    const int kv0 = nt * 32;
    __syncthreads();
    // stage K (16 KB) via global_load_lds, source pre-swizzled
    {
      int rh = l >> 5;                 // row within 2-row chunk
      int pc = (l & 31) * 16;          // physical col byte
#pragma unroll
      for (int i = 0; i < 4; ++i) {
        int c = w * 4 + i;
        int kr = c * 2 + rh;           // 0..31
        int lcb = pc ^ ((kr & 7) << 4);
        gload_lds16(qkv + (size_t)(kv0 + kr) * 6144 + 2048 + h * 256 + (lcb >> 1), &Ks[c * 512]);
      }
    }
    // stage V transposed (reg-staged b64 packs)
    {
      s16x8_t rv[4];
      const unsigned short* Vg = qkv + (size_t)(kv0 + vn0) * 6144 + 4096 + h * 256 + ve0;
#pragma unroll
      for (int rr = 0; rr < 4; ++rr) rv[rr] = *(const s16x8_t*)(Vg + rr * 6144);
#pragma unroll
      for (int j = 0; j < 8; ++j) {
        int e = ve0 + j;
        uint64_t pk = (uint64_t)(unsigned short)rv[0][j] |
                      ((uint64_t)(unsigned short)rv[1][j] << 16) |
                      ((uint64_t)(unsigned short)rv[2][j] << 32) |
                      ((uint64_t)(unsigned short)rv[3][j] << 48);
        int pb = e * 64 + ((vn0 * 2) ^ (((e >> 1) & 3) << 4));
        *(uint64_t*)(&Vt[pb >> 1]) = pk;
      }
    }
    __syncthreads();

    // S = Q Kt : 16x32 per wave
    f32x4_t s[2];
#pragma unroll
    for (int ni = 0; ni < 2; ++ni) s[ni] = (f32x4_t){0.f, 0.f, 0.f, 0.f};
#pragma unroll
    for (int kk = 0; kk < 8; ++kk) {
#pragma unroll
      for (int ni = 0; ni < 2; ++ni) {
        int br = ni * 16 + l15;
        bf16x8_t kb = *(const bf16x8_t*)(&Ks[(br * 512 + ((kk * 64 + lhi * 16) ^ ((br & 7) << 4))) >> 1]);
        s[ni] = __builtin_amdgcn_mfma_f32_16x16x32_bf16(qf[kk], kb, s[ni], 0, 0, 0);
      }
    }

    // online softmax (rows = lhi*4 + r, cols = kv0 + ni*16 + l15)
    float p[2][4];
    float alpha[4];
#pragma unroll
    for (int r = 0; r < 4; ++r) {
      int grow = q0 + w * 16 + lhi * 4 + r;
      float sv[2];
      float mx = -1e30f;
#pragma unroll
      for (int ni = 0; ni < 2; ++ni) {
        float x = s[ni][r] * 0.0625f;
        if (kv0 + ni * 16 + l15 == grow) x = -1e30f;   // masked diagonal
        sv[ni] = x;
        mx = fmaxf(mx, x);
      }
#pragma unroll
      for (int msk = 1; msk < 16; msk <<= 1) mx = fmaxf(mx, __shfl_xor(mx, msk));
      float mn = fmaxf(m_run[r], mx);
      alpha[r] = __expf(m_run[r] - mn);
      m_run[r] = mn;
      float ls = 0.f;
#pragma unroll
      for (int ni = 0; ni < 2; ++ni) {
        float pv = __expf(sv[ni] - mn);
        p[ni][r] = pv;
        ls += pv;
      }
#pragma unroll
      for (int msk = 1; msk < 16; msk <<= 1) ls += __shfl_xor(ls, msk);
      l_run[r] = l_run[r] * alpha[r] + ls;
    }
    // rescale O
#pragma unroll
    for (int et = 0; et < 16; ++et)
#pragma unroll
      for (int r = 0; r < 4; ++r) o[et][r] *= alpha[r];

    // write P to per-wave LDS (bf16), then PV
    unsigned short* Pw = &Ps[w][0];
#pragma unroll
    for (int ni = 0; ni < 2; ++ni)
#pragma unroll
      for (int r = 0; r < 4; ++r) {
        int prow = lhi * 4 + r;
        int pb = prow * 64 + ((((ni * 16 + l15) * 2)) ^ (((prow >> 1) & 3) << 4));
        Pw[pb >> 1] = f2bf(p[ni][r]);
      }
    bf16x8_t pa = *(const bf16x8_t*)(&Pw[(l15 * 64 + ((lhi * 16) ^ (((l15 >> 1) & 3) << 4))) >> 1]);
#pragma unroll
    for (int et = 0; et < 16; ++et) {
      int er = et * 16 + l15;
      bf16x8_t vb = *(const bf16x8_t*)(&Vt[(er * 64 + ((lhi * 16) ^ (((er >> 1) & 3) << 4))) >> 1]);
      o[et] = __builtin_amdgcn_mfma_f32_16x16x32_bf16(pa, vb, o[et], 0, 0, 0);
    }
  }

  // normalize + write attn_cat[n][h*256 + e]
  float inv[4];
#pragma unroll
  for (int r = 0; r < 4; ++r) inv[r] = 1.0f / l_run[r];
#pragma unroll
  for (int et = 0; et < 16; ++et)
#pragma unroll
    for (int r = 0; r < 4; ++r) {
      int grow = q0 + w * 16 + lhi * 4 + r;
      acat[(size_t)grow * 2048 + h * 256 + et * 16 + l15] = f2bf(o[et][r] * inv[r]);
    }
}

// ---------------- LayerNorm: 1 wave per row, 4 rows per block ----------------
__global__ void ln_kernel(const float* __restrict__ u, const float* __restrict__ g,
                          const float* __restrict__ b, float* __restrict__ outf,
                          unsigned short* __restrict__ outb) {
  int row = blockIdx.x * 4 + (threadIdx.x >> 6);
  int l = threadIdx.x & 63;
  const float* ur = u + (size_t)row * 256;
  f32x4_t v = *(const f32x4_t*)(ur + l * 4);
  float s = v[0] + v[1] + v[2] + v[3];
#pragma unroll
  for (int m = 1; m < 64; m <<= 1) s += __shfl_xor(s, m);
  float mu = s * (1.0f / 256.0f);
  f32x4_t d;
  float vs = 0.f;
#pragma unroll
  for (int i = 0; i < 4; ++i) { d[i] = v[i] - mu; vs += d[i] * d[i]; }
#pragma unroll
  for (int m = 1; m < 64; m <<= 1) vs += __shfl_xor(vs, m);
  float rstd = rsqrtf(vs * (1.0f / 256.0f) + 1e-5f);
  f32x4_t gg = *(const f32x4_t*)(g + l * 4);
  f32x4_t bb = *(const f32x4_t*)(b + l * 4);
#pragma unroll
  for (int i = 0; i < 4; ++i) {
    float o = d[i] * rstd * gg[i] + bb[i];
    if (outf) outf[(size_t)row * 256 + l * 4 + i] = o;
    if (outb) outb[(size_t)row * 256 + l * 4 + i] = f2bf(o);
  }
}

// ---------------- launcher ----------------
extern "C" void kernel_launch(void* const* d_in, const int* in_sizes, int n_in,
                              void* d_out, int out_size, void* d_ws, size_t ws_size,
                              hipStream_t stream) {
  const float* x    = (const float*)d_in[0];
  const float* deg  = (const float*)d_in[1];
  const float* WQ   = (const float*)d_in[2];
  const float* WK   = (const float*)d_in[3];
  const float* WV   = (const float*)d_in[4];
  const float* law  = (const float*)d_in[5];
  const float* lab  = (const float*)d_in[6];
  const float* lw   = (const float*)d_in[7];
  const float* lb   = (const float*)d_in[8];
  const float* ln1g = (const float*)d_in[9];
  const float* ln1b = (const float*)d_in[10];
  const float* f1w  = (const float*)d_in[11];
  const float* f1b  = (const float*)d_in[12];
  const float* f2w  = (const float*)d_in[13];
  const float* f2b  = (const float*)d_in[14];
  const float* ln2g = (const float*)d_in[15];
  const float* ln2b = (const float*)d_in[16];

  char* ws = (char*)d_ws;
  size_t off = 0;
  auto alloc = [&](size_t bytes) {
    void* p = ws + off;
    off += (bytes + 255) & ~(size_t)255;
    return p;
  };
  unsigned short* qkvwT = (unsigned short*)alloc((size_t)6144 * 256 * 2);
  unsigned short* lawT  = (unsigned short*)alloc((size_t)256 * 2048 * 2);
  unsigned short* lwT   = (unsigned short*)alloc((size_t)256 * 512 * 2);
  unsigned short* f1T   = (unsigned short*)alloc((size_t)256 * 256 * 2);
  unsigned short* f2T   = (unsigned short*)alloc((size_t)256 * 256 * 2);
  unsigned short* xa    = (unsigned short*)alloc((size_t)NTOK * 512 * 2);
  unsigned short* qkv   = (unsigned short*)alloc((size_t)NTOK * 6144 * 2);
  unsigned short* acat  = (unsigned short*)alloc((size_t)NTOK * 2048 * 2);
  float*          u1    = (float*)alloc((size_t)NTOK * 256 * 4);
  float*          x1f   = (float*)alloc((size_t)NTOK * 256 * 4);
  unsigned short* x1b   = (unsigned short*)alloc((size_t)NTOK * 256 * 2);
  unsigned short* tb    = (unsigned short*)alloc((size_t)NTOK * 256 * 2);
  float*          u2    = (float*)alloc((size_t)NTOK * 256 * 4);

  prep_qkv_w<<<6144, 256, 0, stream>>>(WQ, WK, WV, qkvwT);
  prep_T<<<2048, 256, 0, stream>>>(law, lawT, 2048, 256);
  prep_T<<<512, 256, 0, stream>>>(lw, lwT, 512, 256);
  prep_T<<<256, 256, 0, stream>>>(f1w, f1T, 256, 256);
  prep_T<<<256, 256, 0, stream>>>(f2w, f2T, 256, 256);
  prep_x<<<NTOK, 256, 0, stream>>>(x, xa);

  // QKV: (3072x256)@(256x6144) -> qkv bf16
  gemm_kernel<<<dim3(6144 / 128, NTOK / 128), 256, 0, stream>>>(
      xa, 512, qkvwT, 256, qkv, 6144, 256, nullptr, nullptr, 0, nullptr, 2);

  flash_kernel<<<dim3(NTOK / 64, NHEAD), 256, 0, stream>>>(qkv, acat);

  // attn_out -> xa[:,256:512] bf16, fused (+bias)*rsqrt(deg)
  gemm_kernel<<<dim3(2, NTOK / 128), 256, 0, stream>>>(
      acat, 2048, lawT, 2048, xa + 256, 512, 2048, lab, nullptr, 0, deg, 2 | 4);

  // u1 = [x|a2] @ lin_w + lin_b + x
  gemm_kernel<<<dim3(2, NTOK / 128), 256, 0, stream>>>(
      xa, 512, lwT, 512, u1, 256, 512, lb, x, 256, nullptr, 0);
  ln_kernel<<<NTOK / 4, 256, 0, stream>>>(u1, ln1g, ln1b, x1f, x1b);

  // tb = relu(x1 @ fnn1 + b1)
  gemm_kernel<<<dim3(2, NTOK / 128), 256, 0, stream>>>(
      x1b, 256, f1T, 256, tb, 256, 256, f1b, nullptr, 0, nullptr, 1 | 2);
  // u2 = tb @ fnn2 + b2 + x1
  gemm_kernel<<<dim3(2, NTOK / 128), 256, 0, stream>>>(
      tb, 256, f2T, 256, u2, 256, 256, f2b, x1f, 256, nullptr, 0);
  ln_kernel<<<NTOK / 4, 256, 0, stream>>>(u2, ln2g, ln2b, (float*)d_out, nullptr);
}